// Round 7
// baseline (191.059 us; speedup 1.0000x reference)
//
#include <hip/hip_runtime.h>
#include <math.h>

#define HDIM 256
#define PDIM 256
#define BATCH 8
#define LSEQ 4096
#define MTOT (BATCH * LSEQ)   // 32768
#define CHLEN 128             // chunk = one 128-row M-tile
#define NCHUNK 32             // LSEQ / CHLEN
#define CPAD 136              // LDS C-tile row stride (elems); 68 words/row

typedef __attribute__((ext_vector_type(8))) short bf16x8;   // 8 bf16 = 4 VGPRs
typedef __attribute__((ext_vector_type(4))) float f32x4;

__device__ __forceinline__ unsigned short f2bf(float f) {
    union { float f; unsigned int u; } v; v.f = f;
    unsigned int r = v.u + 0x7FFFu + ((v.u >> 16) & 1u);   // RNE
    return (unsigned short)(r >> 16);
}
__device__ __forceinline__ float bf2f(unsigned int lo16) {
    union { unsigned int u; float f; } v; v.u = lo16 << 16;
    return v.f;
}
__device__ __forceinline__ unsigned int pack2(float a, float b) {
    return (unsigned int)f2bf(a) | ((unsigned int)f2bf(b) << 16);
}

// Fragment-linear layout for [R][K] bf16 (R%16==0, K%32==0), Kt = K/32:
//   tile = (m>>4)*Kt + (k>>5);  lane = (m&15) + 16*((k&31)>>3);  e = k&7
//   addr = tile*512 + lane*8 + e
// A wave's mfma fragment load for (mtile, ktile) = tile*512 + lane*8 -> one
// coalesced global_load_dwordx4 per fragment. No LDS, no barriers.

// ---------------- prep: W1f, W2f (frag layout), par (a, a^128), apw row-major ----------------
__global__ void prep_k(const float* __restrict__ Br, const float* __restrict__ Bi,
                       const float* __restrict__ Cr, const float* __restrict__ Ci,
                       const float* __restrict__ llr, const float* __restrict__ lim,
                       const float* __restrict__ ldl,
                       unsigned short* __restrict__ W1f, unsigned short* __restrict__ W2f,
                       float* __restrict__ par, float* __restrict__ apw) {
    int p = blockIdx.x, h = threadIdx.x;
    float er = expf(llr[p]);          // -Re(lam) > 0
    float im = lim[p];
    float d  = expf(ldl[p]);
    float zr = -er * d, zi = im * d;  // lam*delta
    float ea = expf(zr);
    float ar = ea * cosf(zi), ai = ea * sinf(zi);   // a = exp(lam*delta)
    float dr = -er, di = im;
    float den = dr * dr + di * di;
    float nr = ar - 1.0f, ni = ai;
    float cr = (nr * dr + ni * di) / den;           // coef = (a-1)/lam
    float ci = (ni * dr - nr * di) / den;
    float br = Br[p * HDIM + h], bi = Bi[p * HDIM + h];
    // W1f: R=512 (n=2p re / 2p+1 im), K=256 (k=h), Kt=8
    {
        size_t idx = ((size_t)((2 * p) >> 4) * 8 + (h >> 5)) * 512
                   + ((size_t)((2 * p) & 15) + 16 * ((h & 31) >> 3)) * 8 + (h & 7);
        W1f[idx]     = f2bf(cr * br - ci * bi);
        W1f[idx + 8] = f2bf(cr * bi + ci * br);      // n=2p+1 -> lane+1 -> +8 elems
    }
    // W2f: R=256 (n=h), K=512 (k=2p re / 2p+1 im), Kt=16
    {
        size_t idx = ((size_t)(h >> 4) * 16 + (p >> 4)) * 512
                   + ((size_t)(h & 15) + 16 * (((2 * p) & 31) >> 3)) * 8 + ((2 * p) & 7);
        W2f[idx]     = f2bf(Cr[h * PDIM + p]);
        W2f[idx + 1] = f2bf(-Ci[h * PDIM + p]);
    }
    if (h == 0) {
        par[2 * p] = ar; par[2 * p + 1] = ai;
        float pr = ar, pi = ai;
        apw[2 * p] = pr; apw[2 * p + 1] = pi;        // a^1
        for (int j = 1; j < CHLEN; j++) {
            float tr = pr * ar - pi * ai;
            float ti = pr * ai + pi * ar;
            pr = tr; pi = ti;
            apw[j * 512 + 2 * p]     = pr;           // a^{j+1}
            apw[j * 512 + 2 * p + 1] = pi;
        }
        par[512 + 2 * p] = pr; par[512 + 2 * p + 1] = pi;   // a^128
    }
}

// ---------------- LayerNorm -> hbf in frag layout (R=32768, K=256, Kt=8) ----------------
// block = 16 rows (one mtile), 256 threads: thread t -> row r=t>>4, k-segment s=t&15 (16 cols).
__global__ void ln_k(const float* __restrict__ u, unsigned short* __restrict__ hbf,
                     const float* __restrict__ gamma, const float* __restrict__ beta) {
    const int t = threadIdx.x;
    const int r = t >> 4, s = t & 15;
    const int mtile = blockIdx.x;
    const float* up = u + ((size_t)mtile * 16 + r) * 256 + s * 16;
    float4 v0 = *(const float4*)(up);
    float4 v1 = *(const float4*)(up + 4);
    float4 v2 = *(const float4*)(up + 8);
    float4 v3 = *(const float4*)(up + 12);
    float va[16];
    *(float4*)&va[0] = v0; *(float4*)&va[4] = v1; *(float4*)&va[8] = v2; *(float4*)&va[12] = v3;
    float sum = 0.0f, sq = 0.0f;
    #pragma unroll
    for (int q = 0; q < 16; q++) { sum += va[q]; sq += va[q] * va[q]; }
    #pragma unroll
    for (int o = 1; o < 16; o <<= 1) { sum += __shfl_xor(sum, o); sq += __shfl_xor(sq, o); }
    float mu = sum * (1.0f / 256.0f);
    float rs = rsqrtf(sq * (1.0f / 256.0f) - mu * mu + 1e-5f);
    const float* gp = gamma + s * 16;
    const float* bp = beta + s * 16;
    unsigned int w[8];
    #pragma unroll
    for (int q = 0; q < 8; q++)
        w[q] = pack2((va[2 * q] - mu) * rs * gp[2 * q] + bp[2 * q],
                     (va[2 * q + 1] - mu) * rs * gp[2 * q + 1] + bp[2 * q + 1]);
    // frag store: ktile = s>>1, group g0 = (s&1)*2
    const int g0 = (s & 1) * 2;
    unsigned short* dst = hbf + ((size_t)mtile * 8 + (s >> 1)) * 512 + ((size_t)(r) + 16 * g0) * 8;
    *(uint4*)dst         = make_uint4(w[0], w[1], w[2], w[3]);   // lane_f = r+16*g0
    *(uint4*)(dst + 128) = make_uint4(w[4], w[5], w[6], w[7]);   // lane_f +16 -> +128 elems
}

// ---------------- GEMM1 (no-LDS frag K-loop) + chunk-local scan epilogue ----------------
// Bu[M][512] row-major = localscan(h @ W1^T); last[bm][p] = chunk final (fp32)
__launch_bounds__(256, 2)
__global__ void gemm1_k(const unsigned short* __restrict__ hbf, const unsigned short* __restrict__ W1f,
                        unsigned short* __restrict__ Bu, float* __restrict__ last,
                        const float* __restrict__ par) {
    __shared__ unsigned short C[128 * CPAD];
    const int t = threadIdx.x;
    const int bn = blockIdx.x, bm = blockIdx.y;
    const int lane = t & 63, w = t >> 6;
    const unsigned short* Ab = hbf + ((size_t)(bm * 8 + (w & 1) * 4) * 8) * 512 + lane * 8;
    const unsigned short* Bb = W1f + ((size_t)(bn * 8 + (w >> 1) * 4) * 8) * 512 + lane * 8;

    f32x4 acc[4][4] = {};
    bf16x8 fa[4], fb[4];
    #pragma unroll
    for (int i = 0; i < 4; i++) {
        fa[i] = *(const bf16x8*)(Ab + (size_t)i * 8 * 512);
        fb[i] = *(const bf16x8*)(Bb + (size_t)i * 8 * 512);
    }
    #pragma unroll
    for (int kt = 0; kt < 8; ++kt) {
        bf16x8 na[4], nb[4];
        if (kt < 7) {
            #pragma unroll
            for (int i = 0; i < 4; i++) {
                na[i] = *(const bf16x8*)(Ab + ((size_t)i * 8 + kt + 1) * 512);
                nb[i] = *(const bf16x8*)(Bb + ((size_t)i * 8 + kt + 1) * 512);
            }
        }
        #pragma unroll
        for (int i = 0; i < 4; i++)
            #pragma unroll
            for (int j = 0; j < 4; j++)
                acc[i][j] = __builtin_amdgcn_mfma_f32_16x16x32_bf16(fa[i], fb[j], acc[i][j], 0, 0, 0);
        if (kt < 7) {
            #pragma unroll
            for (int i = 0; i < 4; i++) { fa[i] = na[i]; fb[i] = nb[i]; }
        }
    }

    // store acc -> LDS C (row-major, padded)
    const int wm = (w & 1) * 64, wn = (w >> 1) * 64;
    const int r0 = (lane >> 4) * 4, c0 = lane & 15;
    #pragma unroll
    for (int i = 0; i < 4; i++)
        #pragma unroll
        for (int j = 0; j < 4; j++)
            #pragma unroll
            for (int r = 0; r < 4; r++)
                C[(wm + i * 16 + r0 + r) * CPAD + wn + j * 16 + c0] = f2bf(acc[i][j][r]);
    __syncthreads();

    // zero-seeded local scan over 128 rows, thread = complex col (word stride 68: conflict-free)
    if (t < 64) {
        int pg = bn * 64 + t;
        float ar = par[2 * pg], ai = par[2 * pg + 1];
        float xr = 0.0f, xi = 0.0f;
        unsigned int* Cw = (unsigned int*)C;
        #pragma unroll 8
        for (int s = 0; s < CHLEN; s++) {
            unsigned int v = Cw[s * (CPAD / 2) + t];
            float vr = bf2f(v & 0xFFFFu), vi = bf2f(v >> 16);
            float nr = fmaf(ar, xr, fmaf(-ai, xi, vr));
            float ni = fmaf(ar, xi, fmaf(ai, xr, vi));
            xr = nr; xi = ni;
            Cw[s * (CPAD / 2) + t] = pack2(xr, xi);
        }
        *(float2*)(last + (size_t)(bm * 256 + pg) * 2) = make_float2(xr, xi);
    }
    __syncthreads();

    // coalesced row-major store of xloc to Bu
    {
        int row = t >> 1, ch = (t & 1) * 64;
        unsigned short* dst = Bu + (size_t)(bm * 128 + row) * 512 + bn * 128 + ch;
        const unsigned short* src = &C[row * CPAD + ch];
        #pragma unroll
        for (int q = 0; q < 8; q++)
            *(uint4*)(dst + q * 8) = *(const uint4*)(src + q * 8);
    }
}

// ---------------- carry: load-all then scan; prefix[bm][p] = state entering chunk ----------------
__global__ void carry_k(const float* __restrict__ last, float* __restrict__ prefix,
                        const float* __restrict__ par) {
    int p = threadIdx.x, b = blockIdx.x;
    float Ar = par[512 + 2 * p], Ai = par[512 + 2 * p + 1];   // a^128
    float2 L[NCHUNK];
    #pragma unroll
    for (int c = 0; c < NCHUNK; c++)
        L[c] = *(const float2*)(last + ((size_t)(b * NCHUNK + c) * 256 + p) * 2);
    float Pr = 0.0f, Pi = 0.0f;
    #pragma unroll
    for (int c = 0; c < NCHUNK; c++) {
        *(float2*)(prefix + ((size_t)(b * NCHUNK + c) * 256 + p) * 2) = make_float2(Pr, Pi);
        float nr = fmaf(Ar, Pr, fmaf(-Ai, Pi, L[c].x));
        float ni = fmaf(Ar, Pi, fmaf(Ai, Pr, L[c].y));
        Pr = nr; Pi = ni;
    }
}

// ---------------- apply + layout convert: Buf(frag) = Bu(rowmajor) + a^{j+1}*prefix ----------------
// thread = one 16B group in FRAG order (coalesced writes); reads row-major (coalesced 64B lines).
__global__ void apply_k(const unsigned short* __restrict__ Bu, unsigned short* __restrict__ Buf,
                        const float* __restrict__ apw, const float* __restrict__ prefix) {
    const size_t gidx = (size_t)blockIdx.x * 256 + threadIdx.x;   // 0 .. 2M-1
    const int tile = (int)(gidx >> 6), lane_f = (int)(gidx & 63);
    const int m  = (tile >> 4) * 16 + (lane_f & 15);    // global row
    const int k8 = (tile & 15) * 4 + (lane_f >> 4);     // 8-elem group in k
    const int j  = m & 127;                              // row within chunk
    const int bc = m >> 7;                               // b*32 + c
    uint4 v4 = *(const uint4*)(Bu + (size_t)m * 512 + k8 * 8);
    float4 f0 = *(const float4*)(apw + (size_t)j * 512 + k8 * 8);
    float4 f1 = *(const float4*)(apw + (size_t)j * 512 + k8 * 8 + 4);
    float4 p0 = *(const float4*)(prefix + ((size_t)bc * 256 + k8 * 4) * 2);
    float4 p1 = *(const float4*)(prefix + ((size_t)bc * 256 + k8 * 4) * 2 + 4);
    float fv[8], pv[8];
    *(float4*)&fv[0] = f0; *(float4*)&fv[4] = f1;
    *(float4*)&pv[0] = p0; *(float4*)&pv[4] = p1;
    unsigned int vin[4] = {v4.x, v4.y, v4.z, v4.w};
    unsigned int vout[4];
    #pragma unroll
    for (int i = 0; i < 4; i++) {
        float vr = bf2f(vin[i] & 0xFFFFu), vi = bf2f(vin[i] >> 16);
        float ar = fv[2 * i], ai = fv[2 * i + 1];
        float Pr = pv[2 * i], Pi = pv[2 * i + 1];
        float xr = fmaf(ar, Pr, fmaf(-ai, Pi, vr));
        float xi = fmaf(ar, Pi, fmaf(ai, Pr, vi));
        vout[i] = pack2(xr, xi);
    }
    *(uint4*)(Buf + gidx * 8) = make_uint4(vout[0], vout[1], vout[2], vout[3]);
}

// ---------------- GEMM2 (no-LDS frag K-loop) + gelu epilogue ----------------
// out[M][256] = u + gelu( x(frag) @ W2f^T )
__launch_bounds__(256, 2)
__global__ void gemm2_k(const unsigned short* __restrict__ Buf, const unsigned short* __restrict__ W2f,
                        float* __restrict__ out, const float* __restrict__ u) {
    const int t = threadIdx.x;
    const int bn = blockIdx.x, bm = blockIdx.y;
    const int lane = t & 63, w = t >> 6;
    const unsigned short* Ab = Buf + ((size_t)(bm * 8 + (w & 1) * 4) * 16) * 512 + lane * 8;
    const unsigned short* Bb = W2f + ((size_t)(bn * 8 + (w >> 1) * 4) * 16) * 512 + lane * 8;

    f32x4 acc[4][4] = {};
    bf16x8 fa[4], fb[4];
    #pragma unroll
    for (int i = 0; i < 4; i++) {
        fa[i] = *(const bf16x8*)(Ab + (size_t)i * 16 * 512);
        fb[i] = *(const bf16x8*)(Bb + (size_t)i * 16 * 512);
    }
    #pragma unroll
    for (int kt = 0; kt < 16; ++kt) {
        bf16x8 na[4], nb[4];
        if (kt < 15) {
            #pragma unroll
            for (int i = 0; i < 4; i++) {
                na[i] = *(const bf16x8*)(Ab + ((size_t)i * 16 + kt + 1) * 512);
                nb[i] = *(const bf16x8*)(Bb + ((size_t)i * 16 + kt + 1) * 512);
            }
        }
        #pragma unroll
        for (int i = 0; i < 4; i++)
            #pragma unroll
            for (int j = 0; j < 4; j++)
                acc[i][j] = __builtin_amdgcn_mfma_f32_16x16x32_bf16(fa[i], fb[j], acc[i][j], 0, 0, 0);
        if (kt < 15) {
            #pragma unroll
            for (int i = 0; i < 4; i++) { fa[i] = na[i]; fb[i] = nb[i]; }
        }
    }

    const int wm = (w & 1) * 64, wn = (w >> 1) * 64;
    const int r0 = (lane >> 4) * 4, c0 = lane & 15;
    #pragma unroll
    for (int i = 0; i < 4; i++) {
        #pragma unroll
        for (int r = 0; r < 4; r++) {
            const size_t rowoff = (size_t)(bm * 128 + wm + i * 16 + r0 + r) * 256;
            #pragma unroll
            for (int j = 0; j < 4; j++) {
                const int col = bn * 128 + wn + j * 16 + c0;
                float y = acc[i][j][r];
                float z = 0.7978845608f * fmaf(0.044715f * y * y, y, y);
                float e = __expf(2.0f * z);
                float th = 1.0f - 2.0f / (e + 1.0f);
                out[rowoff + col] = u[rowoff + col] + 0.5f * y * (1.0f + th);
            }
        }
    }
}

extern "C" void kernel_launch(void* const* d_in, const int* in_sizes, int n_in,
                              void* d_out, int out_size, void* d_ws, size_t ws_size,
                              hipStream_t stream) {
    const float* u   = (const float*)d_in[0];
    const float* llr = (const float*)d_in[1];
    const float* lim = (const float*)d_in[2];
    const float* Br  = (const float*)d_in[3];
    const float* Bi  = (const float*)d_in[4];
    const float* Cr  = (const float*)d_in[5];
    const float* Ci  = (const float*)d_in[6];
    const float* ldl = (const float*)d_in[7];
    const float* gam = (const float*)d_in[8];
    const float* bet = (const float*)d_in[9];
    float* out = (float*)d_out;

    float* ws     = (float*)d_ws;
    float* par    = ws;                                   // 1024 floats (a, a^128)
    float* apw    = ws + 1024;                            // 128*512 floats (a^{j+1}, row-major)
    float* last   = apw + 128 * 512;                      // 256*256*2 floats
    float* prefix = last + 256 * 256 * 2;                 // 256*256*2 floats
    unsigned short* W1f = (unsigned short*)(prefix + 256 * 256 * 2);   // frag [512][256]
    unsigned short* W2f = W1f + 512 * HDIM;               // frag [256][512]
    unsigned short* hbf = W2f + HDIM * 512;               // frag [32768][256]
    unsigned short* Bu  = hbf + (size_t)MTOT * HDIM;      // row-major [32768][512] (xloc)
    unsigned short* Buf = Bu + (size_t)MTOT * 512;        // frag [32768][512] (x)

    prep_k<<<PDIM, HDIM, 0, stream>>>(Br, Bi, Cr, Ci, llr, lim, ldl, W1f, W2f, par, apw);
    ln_k<<<MTOT / 16, 256, 0, stream>>>(u, hbf, gam, bet);

    gemm1_k<<<dim3(4, MTOT / 128), 256, 0, stream>>>(hbf, W1f, Bu, last, par);

    carry_k<<<BATCH, PDIM, 0, stream>>>(last, prefix, par);

    apply_k<<<(MTOT * 512 / 8) / 256, 256, 0, stream>>>(Bu, Buf, apw, prefix);

    gemm2_k<<<dim3(2, MTOT / 128), 256, 0, stream>>>(Buf, W2f, out, u);
}